// Round 1
// baseline (564.791 us; speedup 1.0000x reference)
//
#include <hip/hip_runtime.h>
#include <hip/hip_bf16.h>

#define B_ROWS 8192
#define D_DIM  256
#define QB     64
#define KB     64
#define ALPHA  0.8f
// TAU * log2(e) = 3.0 * 1.4426950408889634
#define TAU_LOG2E 4.328085122666890f

typedef __attribute__((ext_vector_type(8))) short bf16x8;
typedef __attribute__((ext_vector_type(4))) float f32x4;
typedef __attribute__((ext_vector_type(4))) unsigned short ushort4v;

__device__ inline unsigned short f2bf(float f) {
    unsigned int u = __builtin_bit_cast(unsigned int, f);
    u += 0x7FFF + ((u >> 16) & 1);   // RNE (finite values)
    return (unsigned short)(u >> 16);
}

// ---------------- Kernel A: gather + row-normalize, emit f32 + bf16 copies --
__global__ __launch_bounds__(64) void k_gather_norm(
    const float* __restrict__ ue, const float* __restrict__ ie,
    const int* __restrict__ u, const int* __restrict__ p,
    float* __restrict__ Xf, unsigned short* __restrict__ Xh,
    float* __restrict__ out)
{
    const int b = blockIdx.x;        // 0..16383
    const int lane = threadIdx.x;    // 0..63
    if (b == 0 && lane == 0) out[0] = 0.0f;   // init accumulator (d_out is poisoned)
    const int m = b >> 13;
    const int r = b & 8191;
    const float* src = (m == 0) ? (ue + (size_t)u[r] * D_DIM)
                                : (ie + (size_t)p[r] * D_DIM);
    float4 v = ((const float4*)src)[lane];
    float ss = v.x*v.x + v.y*v.y + v.z*v.z + v.w*v.w;
    #pragma unroll
    for (int mask = 32; mask; mask >>= 1) ss += __shfl_xor(ss, mask);
    const float inv = 1.0f / sqrtf(ss);
    v.x *= inv; v.y *= inv; v.z *= inv; v.w *= inv;
    const size_t off = (size_t)(m * B_ROWS + r) * D_DIM + lane * 4;
    *(float4*)(Xf + off) = v;
    ushort4v h = { f2bf(v.x), f2bf(v.y), f2bf(v.z), f2bf(v.w) };
    *(ushort4v*)(Xh + off) = h;
}

// ---------------- Kernel T: bf16 transpose [2][8192][256] -> [2][256][8192] --
__global__ __launch_bounds__(256) void k_transpose(
    const unsigned short* __restrict__ Xh, unsigned short* __restrict__ Xht)
{
    __shared__ unsigned short tile[64 * 84];   // row stride 84 elems (168B) vs bank conflicts
    const int bid = blockIdx.x;                // 0..1023
    const int m = bid >> 9;
    const int t = bid & 511;
    const int rt = t >> 2, ct = t & 3;
    const int r0 = rt * 64, c0 = ct * 64;
    const int tid = threadIdx.x;
    const unsigned short* src = Xh + (size_t)m * B_ROWS * D_DIM;
    unsigned short* dst = Xht + (size_t)m * D_DIM * B_ROWS;
    #pragma unroll
    for (int ph = 0; ph < 2; ++ph) {
        const int row = ph * 32 + (tid >> 3);
        const int ch = tid & 7;
        const unsigned short* s = src + (size_t)(r0 + row) * D_DIM + c0 + ch * 8;
        ushort4v a = *(const ushort4v*)s;
        ushort4v b = *(const ushort4v*)(s + 4);
        *(ushort4v*)(&tile[row * 84 + ch * 8]) = a;
        *(ushort4v*)(&tile[row * 84 + ch * 8 + 4]) = b;
    }
    __syncthreads();
    #pragma unroll
    for (int ph = 0; ph < 2; ++ph) {
        const int d = ph * 32 + (tid >> 3);
        const int kc = tid & 7;
        ushort4v lo = { tile[(kc*8+0)*84 + d], tile[(kc*8+1)*84 + d],
                        tile[(kc*8+2)*84 + d], tile[(kc*8+3)*84 + d] };
        ushort4v hi = { tile[(kc*8+4)*84 + d], tile[(kc*8+5)*84 + d],
                        tile[(kc*8+6)*84 + d], tile[(kc*8+7)*84 + d] };
        unsigned short* o = dst + (size_t)(c0 + d) * B_ROWS + r0 + kc * 8;
        *(ushort4v*)o = lo;
        *(ushort4v*)(o + 4) = hi;
    }
}

// ---------------- Kernel B: flash spec-smooth --------------------------------
// grid = 256 blocks (2 matrices x 128 Q-blocks), block = 512 threads (8 waves)
// Per block: Q-tile 64 rows. Iterate 128 KV-tiles of 64.
// Wave w: QK^T rows (w&3)*16, cols (w>>2)*32; PV rows (w&3)*16, d (w>>2)*128.
__global__ __launch_bounds__(512) void k_flash(
    const unsigned short* __restrict__ Xh,   // [2][8192][256] bf16
    const unsigned short* __restrict__ Xht,  // [2][256][8192] bf16
    float* __restrict__ Xf)                  // [2][8192][256] f32; overwritten with Y
{
    __shared__ unsigned char Qls[64 * 512];    // 32KB, bf16 rows of 512B, XOR-swizzled
    __shared__ unsigned char Kls[64 * 512];    // 32KB
    __shared__ unsigned char Vtls[256 * 128];  // 32KB: 256 d-rows x 64 kv (128B)
    __shared__ unsigned char Pls[64 * 128];    // 8KB: 64 rows x 64 bf16
    __shared__ float lsum_sh[2][QB];
    __shared__ float nrm_sh[2][QB];

    const int tid = threadIdx.x;
    const int lane = tid & 63;
    const int w = tid >> 6;
    const int wrg = (w & 3) * 16;     // row-group base within Q tile
    const int wh = w >> 2;            // half id
    const int m = blockIdx.x >> 7;
    const int q0 = (blockIdx.x & 127) * QB;

    const unsigned short* Xm  = Xh  + (size_t)m * B_ROWS * D_DIM;
    const unsigned short* Xtm = Xht + (size_t)m * D_DIM * B_ROWS;
    float* Xfm = Xf + (size_t)m * B_ROWS * D_DIM;

    // stage Q tile (once)
    #pragma unroll
    for (int it = 0; it < 4; ++it) {
        const int c = it * 512 + tid;
        const int row = c >> 5, dch = c & 31;
        float4 a = *(const float4*)(Xm + (size_t)(q0 + row) * D_DIM + dch * 8);
        *(float4*)(Qls + row * 512 + ((dch * 16) ^ ((row & 7) << 4))) = a;
    }

    f32x4 o[8];
    #pragma unroll
    for (int i = 0; i < 8; ++i) o[i] = (f32x4){0.f, 0.f, 0.f, 0.f};
    float lsum[4] = {0.f, 0.f, 0.f, 0.f};
    const int cfbase = wh * 32;
    const int dbase  = wh * 128;

    for (int kt = 0; kt < B_ROWS / KB; ++kt) {
        const int kv0 = kt * KB;
        __syncthreads();   // prev iter's LDS reads complete before restage
        #pragma unroll
        for (int it = 0; it < 4; ++it) {
            const int c = it * 512 + tid;
            const int row = c >> 5, dch = c & 31;
            float4 a = *(const float4*)(Xm + (size_t)(kv0 + row) * D_DIM + dch * 8);
            *(float4*)(Kls + row * 512 + ((dch * 16) ^ ((row & 7) << 4))) = a;
        }
        #pragma unroll
        for (int it = 0; it < 4; ++it) {
            const int c = it * 512 + tid;
            const int d = c >> 3, kc = c & 7;
            float4 a = *(const float4*)(Xtm + (size_t)d * B_ROWS + kv0 + kc * 8);
            *(float4*)(Vtls + d * 128 + ((kc * 16) ^ ((d & 7) << 4))) = a;
        }
        __syncthreads();

        // ---- QK^T: S[16 x 32] for this wave
        f32x4 s0 = {0.f,0.f,0.f,0.f}, s1 = {0.f,0.f,0.f,0.f};
        const int arow = wrg + (lane & 15);
        const int brow0 = cfbase + (lane & 15);
        const int brow1 = brow0 + 16;
        #pragma unroll
        for (int kk = 0; kk < 8; ++kk) {
            const int kb = kk * 64 + ((lane >> 4) * 16);
            bf16x8 aQ  = *(const bf16x8*)(Qls + arow  * 512 + (kb ^ ((arow  & 7) << 4)));
            bf16x8 bK0 = *(const bf16x8*)(Kls + brow0 * 512 + (kb ^ ((brow0 & 7) << 4)));
            bf16x8 bK1 = *(const bf16x8*)(Kls + brow1 * 512 + (kb ^ ((brow1 & 7) << 4)));
            s0 = __builtin_amdgcn_mfma_f32_16x16x32_bf16(aQ, bK0, s0, 0, 0, 0);
            s1 = __builtin_amdgcn_mfma_f32_16x16x32_bf16(aQ, bK1, s1, 0, 0, 0);
        }
        // ---- P = exp(TAU*S); accumulate row-sums; write bf16 P to LDS
        #pragma unroll
        for (int i = 0; i < 4; ++i) {
            const float p0 = exp2f(s0[i] * TAU_LOG2E);
            const float p1 = exp2f(s1[i] * TAU_LOG2E);
            lsum[i] += p0 + p1;
            const int prow = wrg + (lane >> 4) * 4 + i;
            const int pc = cfbase + (lane & 15);
            *(unsigned short*)(Pls + prow * 128 + (( pc       * 2) ^ ((prow & 7) << 4))) = f2bf(p0);
            *(unsigned short*)(Pls + prow * 128 + (((pc + 16) * 2) ^ ((prow & 7) << 4))) = f2bf(p1);
        }
        __syncthreads();
        // ---- PV: O[16 x 128] += P[16 x 64] @ V[64 x 128]
        #pragma unroll
        for (int kk = 0; kk < 2; ++kk) {
            const int kb = kk * 64 + ((lane >> 4) * 16);
            const int parow = wrg + (lane & 15);
            bf16x8 aP = *(const bf16x8*)(Pls + parow * 128 + (kb ^ ((parow & 7) << 4)));
            #pragma unroll
            for (int nf = 0; nf < 8; ++nf) {
                const int drow = dbase + nf * 16 + (lane & 15);
                bf16x8 bV = *(const bf16x8*)(Vtls + drow * 128 + (kb ^ ((drow & 7) << 4)));
                o[nf] = __builtin_amdgcn_mfma_f32_16x16x32_bf16(aP, bV, o[nf], 0, 0, 0);
            }
        }
    }

    // ---- epilogue: softmax denominator, y = x - alpha*O/l, norm-rescale -----
    #pragma unroll
    for (int i = 0; i < 4; ++i) {
        float v = lsum[i];
        v += __shfl_xor(v, 1); v += __shfl_xor(v, 2);
        v += __shfl_xor(v, 4); v += __shfl_xor(v, 8);
        lsum[i] = v;
    }
    if ((lane & 15) == 0) {
        #pragma unroll
        for (int i = 0; i < 4; ++i)
            lsum_sh[wh][wrg + (lane >> 4) * 4 + i] = lsum[i];
    }
    __syncthreads();

    float nrm[4] = {0.f, 0.f, 0.f, 0.f};
    #pragma unroll
    for (int nf = 0; nf < 8; ++nf) {
        #pragma unroll
        for (int i = 0; i < 4; ++i) {
            const int rl = wrg + (lane >> 4) * 4 + i;
            const int col = dbase + nf * 16 + (lane & 15);
            const float x = Xfm[(size_t)(q0 + rl) * D_DIM + col];
            const float lt = lsum_sh[0][rl] + lsum_sh[1][rl];
            const float y = x - (ALPHA / lt) * o[nf][i];
            o[nf][i] = y;
            nrm[i] += y * y;
        }
    }
    #pragma unroll
    for (int i = 0; i < 4; ++i) {
        float v = nrm[i];
        v += __shfl_xor(v, 1); v += __shfl_xor(v, 2);
        v += __shfl_xor(v, 4); v += __shfl_xor(v, 8);
        nrm[i] = v;
    }
    if ((lane & 15) == 0) {
        #pragma unroll
        for (int i = 0; i < 4; ++i)
            nrm_sh[wh][wrg + (lane >> 4) * 4 + i] = nrm[i];
    }
    __syncthreads();
    #pragma unroll
    for (int nf = 0; nf < 8; ++nf) {
        #pragma unroll
        for (int i = 0; i < 4; ++i) {
            const int rl = wrg + (lane >> 4) * 4 + i;
            const int col = dbase + nf * 16 + (lane & 15);
            const float scale = sqrtf(nrm_sh[0][rl] + nrm_sh[1][rl]);  // * SHRINK_NORM(=1)
            Xfm[(size_t)(q0 + rl) * D_DIM + col] = o[nf][i] * scale;
        }
    }
}

// ---------------- Kernel C: loss = mean(log1p(exp(-dot(fu,fp)))) -------------
__global__ __launch_bounds__(256) void k_loss(
    const float* __restrict__ Yu, const float* __restrict__ Yp,
    float* __restrict__ out)
{
    const int wid = blockIdx.x * 4 + (threadIdx.x >> 6);   // row 0..8191
    const int lane = threadIdx.x & 63;
    const float4 a = *(const float4*)(Yu + (size_t)wid * D_DIM + lane * 4);
    const float4 b = *(const float4*)(Yp + (size_t)wid * D_DIM + lane * 4);
    float dot = a.x*b.x + a.y*b.y + a.z*b.z + a.w*b.w;
    #pragma unroll
    for (int mask = 32; mask; mask >>= 1) dot += __shfl_xor(dot, mask);
    if (lane == 0) {
        const float term = log1pf(expf(-dot));   // = -log(sigmoid(dot))
        atomicAdd(out, term * (1.0f / 8192.0f));
    }
}

extern "C" void kernel_launch(void* const* d_in, const int* in_sizes, int n_in,
                              void* d_out, int out_size, void* d_ws, size_t ws_size,
                              hipStream_t stream) {
    const float* ue = (const float*)d_in[0];
    const float* ie = (const float*)d_in[1];
    const int*   u  = (const int*)d_in[2];
    const int*   p  = (const int*)d_in[3];
    float* out = (float*)d_out;

    char* ws = (char*)d_ws;
    float* Xf            = (float*)ws;                              // 16 MB: [2][8192][256] f32 (becomes Y)
    unsigned short* Xh   = (unsigned short*)(ws + (16u << 20));     //  8 MB: [2][8192][256] bf16
    unsigned short* Xht  = (unsigned short*)(ws + (24u << 20));     //  8 MB: [2][256][8192] bf16

    k_gather_norm<<<16384, 64, 0, stream>>>(ue, ie, u, p, Xf, Xh, out);
    k_transpose <<<1024, 256, 0, stream>>>(Xh, Xht);
    k_flash     <<<256, 512, 0, stream>>>(Xh, Xht, Xf);
    k_loss      <<<2048, 256, 0, stream>>>(Xf, Xf + (size_t)B_ROWS * D_DIM, out);
}